// Round 2
// 978.561 us; speedup vs baseline: 1.0249x; 1.0249x over previous
//
#include <hip/hip_runtime.h>

// GoL CNN v4 (resubmit — prior round was an infra failure, not a kernel fail):
// per layer GEMM M=32(co) x N=16384(b,oy,ox) x K=CIN*1024 via
// mfma_f32_32x32x16_f16. Changes vs v3:
//  - consecutive-ky wave ownership (ky = 4w..4w+3): acc1's B-row(ky) ==
//    acc0's B-row(ky+2) -> 12 LDS gathers instead of 16 per wave per c.
//  - K-loop barrier is lgkmcnt(0)-only + raw s_barrier: weight loads stay
//    in flight across the barrier (no vmcnt(0) drain per iteration).
//  - A-fragment double buffer via 2x-unrolled loop (no reg copy -> no
//    forced vmcnt(0)); loadRow issued before loadA so ds_write waits vmcnt(8).

typedef _Float16 f16;
typedef _Float16 f16x8 __attribute__((ext_vector_type(8)));
typedef float f32x4 __attribute__((ext_vector_type(4)));
typedef float f32x16 __attribute__((ext_vector_type(16)));

// iterated wrap-pad index map, j in [0,94): middle j-31; borders alternate.
__device__ __forceinline__ int mwrap(int j) {
  int t = j - 31;
  if ((unsigned)t <= 31u) return t;          // middle
  if (t < 0) return (j & 1) ? 0 : 31;        // left border
  return (j & 1) ? 0 : 31;                   // right border
}

// hpad layout: [16b][32ch][32y][96x] f16 (x' in [0,94) valid)
// Wf frag-major: per layer, chunk=(c*32+ky)*2+kxh, then [lane(64)][8 f16]
//   lane: co=lane&31, s=lane>>5; elements w[co][c][ky][kxh*16+s*8+j]

template <int CIN, bool RELU, bool PRE>
__global__ __launch_bounds__(512, 2) void gemm3(
    const void* __restrict__ Wv,       // PRE: f16 frag-major; else fp32 raw
    const f16* __restrict__ hp_in,     // [16][CIN][32][96]
    const float* __restrict__ bias,    // [32]
    f16* __restrict__ hp_out) {        // [16][32][32][96]
  __shared__ __align__(16) f16 rowbuf[2][32][96];  // 12 KB
  __shared__ float Red[8][2][1024];                // 64 KB

  const int tid = threadIdx.x;
  const int lane = tid & 63;
  const int w = tid >> 6;        // wave 0..7: owns ky in {4w..4w+3}
  const int ox = lane & 31;      // B n-index / A m-index (co)
  const int s = lane >> 5;       // k-half within mfma

  const int pair0 = blockIdx.x * 2;
  const int b = pair0 >> 5;
  const int oy0 = pair0 & 31;    // pair0 even -> oy0, oy0+1 same batch

  // row staging decode: 384 units of f16x8 cover 32 rows x 96
  const int rrow = tid / 12, rseg = tid - rrow * 12;  // valid if tid<384

  // input rows needed by this wave (loop-invariant across c):
  // acc0 (row oy0):   y = mwrap(2*oy0 + 4w + kyi)        -> j = kyi
  // acc1 (row oy0+1): y = mwrap(2*oy0 + 2 + 4w + kyi)    -> j = kyi+2
  int ybase[6];
#pragma unroll
  for (int j = 0; j < 6; ++j) ybase[j] = mwrap(2 * oy0 + 4 * w + j);

  f32x16 acc0 = {}, acc1 = {};   // per pair
  f16x8 A0[8], A1[8];
  f16x8 stg = {};

  auto loadA = [&](int c, f16x8* dst) {
#pragma unroll
    for (int kyi = 0; kyi < 4; ++kyi) {
#pragma unroll
      for (int kxh = 0; kxh < 2; ++kxh) {
        const int ky = 4 * w + kyi;
        const int chunk = (c * 32 + ky) * 2 + kxh;
        if constexpr (PRE) {
          const f16* Wl = (const f16*)Wv;
          dst[kyi * 2 + kxh] = *(const f16x8*)(Wl + (size_t)chunk * 512 + lane * 8);
        } else {
          const float* Wl = (const float*)Wv;
          const float* sp = Wl + (((size_t)(ox * CIN + c) * 32 + ky) * 32 + kxh * 16 + s * 8);
          f32x4 u0 = *(const f32x4*)sp;
          f32x4 u1 = *(const f32x4*)(sp + 4);
          f16x8 v;
          v[0] = (f16)u0[0]; v[1] = (f16)u0[1]; v[2] = (f16)u0[2]; v[3] = (f16)u0[3];
          v[4] = (f16)u1[0]; v[5] = (f16)u1[1]; v[6] = (f16)u1[2]; v[7] = (f16)u1[3];
          dst[kyi * 2 + kxh] = v;
        }
      }
    }
  };
  auto loadRow = [&](int c) {
    if (tid < 384)
      stg = *(const f16x8*)(hp_in + ((size_t)(b * CIN + c) * 32 + rrow) * 96 + rseg * 8);
  };
  auto writeRow = [&](int nb) {
    if (tid < 384) *(f16x8*)(&rowbuf[nb][rrow][rseg * 8]) = stg;
  };

  // One K-step: compute channel c with A-regs Ause, prefetch c+1 into Apre.
  auto body = [&](int c, const f16x8* Ause, f16x8* Apre) {
    const int buf = c & 1;
    const bool pre = (c + 1 < CIN);
    if (pre) {
      loadRow(c + 1);              // oldest VMEM -> ds_write waits vmcnt(8)
      __builtin_amdgcn_sched_barrier(0);
      loadA(c + 1, Apre);          // 8 (or 16) VMEM, consumed next step
    }
    // 12 unique B fragments (6 rows x 2 kxh)
    f16x8 F[6][2];
#pragma unroll
    for (int j = 0; j < 6; ++j) {
      const int* R = (const int*)(&rowbuf[buf][ybase[j]][0]);
#pragma unroll
      for (int kxh = 0; kxh < 2; ++kxh) {
        const int bi = ox + 4 * s + 8 * kxh;
        int4 t;
        t.x = R[bi]; t.y = R[bi + 1]; t.z = R[bi + 2]; t.w = R[bi + 3];
        F[j][kxh] = __builtin_bit_cast(f16x8, t);
      }
    }
#pragma unroll
    for (int kyi = 0; kyi < 4; ++kyi) {
#pragma unroll
      for (int kxh = 0; kxh < 2; ++kxh) {
        const f16x8 a = Ause[kyi * 2 + kxh];
        acc0 = __builtin_amdgcn_mfma_f32_32x32x16_f16(a, F[kyi][kxh], acc0, 0, 0, 0);
        acc1 = __builtin_amdgcn_mfma_f32_32x32x16_f16(a, F[kyi + 2][kxh], acc1, 0, 0, 0);
      }
    }
    if (pre) writeRow(buf ^ 1);
    // Producer-visibility barrier: drain LDS ops only; weight loads for
    // c+1 stay in flight across the barrier (consumed after it, waitcnt
    // inserted at use). Raw s_barrier does not auto-drain vmcnt.
    asm volatile("s_waitcnt lgkmcnt(0)" ::: "memory");
    __builtin_amdgcn_sched_barrier(0);
    __builtin_amdgcn_s_barrier();
  };

  loadA(0, A0);
  loadRow(0);
  writeRow(0);
  __syncthreads();

  if constexpr (CIN == 1) {
    body(0, A0, A1);
  } else {
#pragma unroll 1
    for (int c = 0; c < CIN; c += 2) {
      body(c, A0, A1);
      body(c + 1, A1, A0);
    }
  }

  // one-shot 8-way K reduction: every wave dumps, all 512 threads re-reduce
#pragma unroll
  for (int r = 0; r < 16; ++r) {
    Red[w][0][r * 64 + lane] = acc0[r];
    Red[w][1][r * 64 + lane] = acc1[r];
  }
  __syncthreads();

#pragma unroll
  for (int k4 = 0; k4 < 4; ++k4) {
    const int o = tid + 512 * k4;          // 2048 outputs: [p][co][ox]
    const int p = o >> 10, co = (o >> 5) & 31, oxx = o & 31;
    const int idx = ((co & 3) + 4 * (co >> 3)) * 64 + ((co >> 2) & 1) * 32 + oxx;
    float v = bias[co];
#pragma unroll
    for (int w8 = 0; w8 < 8; ++w8) v += Red[w8][p][idx];
    if (RELU) v = fmaxf(v, 0.f);
    const f16 hv = (f16)v;
    f16* base = hp_out + ((size_t)(b * 32 + co) * 32 + (oy0 + p)) * 96;
    base[oxx + 31] = hv;
    if (oxx == 0) {
#pragma unroll
      for (int j = 1; j <= 29; j += 2) base[j] = hv;
#pragma unroll
      for (int j = 63; j <= 93; j += 2) base[j] = hv;
    }
    if (oxx == 31) {
#pragma unroll
      for (int j = 0; j <= 30; j += 2) base[j] = hv;
#pragma unroll
      for (int j = 64; j <= 92; j += 2) base[j] = hv;
    }
  }
}

// x (fp32 [16][1][32][32]) -> xpad f16 [16][1][32][96]
__global__ void pad_x_kernel(const float* __restrict__ x, f16* __restrict__ xp) {
  const int i = blockIdx.x * 256 + threadIdx.x;  // 16*32*94 = 48128
  if (i >= 48128) return;
  const int bq = i / 3008, r = i - bq * 3008;
  const int y = r / 94, j = r - y * 94;
  xp[bq * 3072 + y * 96 + j] = (f16)x[(bq * 32 + y) * 32 + mwrap(j)];
}

// build frag-major f16 weights: in_w (64 chunks) + 20 hidden layers (2048 each)
__global__ void convert_w3(const float* __restrict__ in_w,
                           const float* __restrict__ convs_w,
                           f16* __restrict__ WfIn, f16* __restrict__ WfH) {
  const int total = 4096 + 20 * 131072;  // units of (chunk,lane)
  for (int g = blockIdx.x * blockDim.x + threadIdx.x; g < total;
       g += gridDim.x * blockDim.x) {
    const float* src;
    f16* dst;
    int chunk, lanE, c, ky, kxh;
    if (g < 4096) {
      chunk = g >> 6; lanE = g & 63;
      kxh = chunk & 1; ky = chunk >> 1; c = 0;
      const int co = lanE & 31, ss = lanE >> 5;
      src = in_w + ((size_t)(co * 1 + 0) * 32 + ky) * 32 + kxh * 16 + ss * 8;
      dst = WfIn + (size_t)chunk * 512 + lanE * 8;
    } else {
      const int h = g - 4096;
      const int layer = h >> 17, r = h & 131071;
      chunk = r >> 6; lanE = r & 63;
      kxh = chunk & 1;
      const int t = chunk >> 1;
      ky = t & 31; c = t >> 5;
      const int co = lanE & 31, ss = lanE >> 5;
      src = convs_w + (size_t)layer * 1048576 +
            ((size_t)(co * 32 + c) * 32 + ky) * 32 + kxh * 16 + ss * 8;
      dst = WfH + (size_t)layer * 1048576 + (size_t)chunk * 512 + lanE * 8;
    }
    f32x4 u0 = *(const f32x4*)src;
    f32x4 u1 = *(const f32x4*)(src + 4);
    f16x8 v;
    v[0] = (f16)u0[0]; v[1] = (f16)u0[1]; v[2] = (f16)u0[2]; v[3] = (f16)u0[3];
    v[4] = (f16)u1[0]; v[5] = (f16)u1[1]; v[6] = (f16)u1[2]; v[7] = (f16)u1[3];
    *(f16x8*)dst = v;
  }
}

// 1x1 out conv from hpad final: out[b][0][oy][ox] fp32
__global__ void out_conv3(const f16* __restrict__ hp,
                          const float* __restrict__ ow,
                          const float* __restrict__ ob,
                          float* __restrict__ out) {
  const int o = blockIdx.x * 256 + threadIdx.x;  // 16384
  const int b = o >> 10, oy = (o >> 5) & 31, oxx = o & 31;
  float s = ob[0];
#pragma unroll
  for (int c = 0; c < 32; ++c)
    s += ow[c] * (float)hp[((size_t)(b * 32 + c) * 32 + oy) * 96 + oxx + 31];
  out[o] = s;
}

extern "C" void kernel_launch(void* const* d_in, const int* in_sizes, int n_in,
                              void* d_out, int out_size, void* d_ws,
                              size_t ws_size, hipStream_t stream) {
  const float* x = (const float*)d_in[0];
  const float* in_w = (const float*)d_in[1];
  const float* in_b = (const float*)d_in[2];
  const float* convs_w = (const float*)d_in[3];
  const float* convs_b = (const float*)d_in[4];
  const float* out_w = (const float*)d_in[5];
  const float* out_b = (const float*)d_in[6];
  float* out = (float*)d_out;

  char* ws = (char*)d_ws;
  f16* xpad = (f16*)ws;                               //    98,304 B
  f16* hpA = (f16*)(ws + 98304);                      // 3,145,728 B
  f16* hpB = (f16*)(ws + 98304 + 3145728);            // 3,145,728 B
  f16* WfIn = (f16*)(ws + 6389760);                   //    65,536 B
  f16* WfH = (f16*)(ws + 6455296);                    // 41,943,040 B
  const bool pre = (ws_size >= 48398336ull);

  pad_x_kernel<<<188, 256, 0, stream>>>(x, xpad);
  if (pre) convert_w3<<<2048, 256, 0, stream>>>(in_w, convs_w, WfIn, WfH);

  if (pre)
    gemm3<1, false, true><<<256, 512, 0, stream>>>(WfIn, xpad, in_b, hpA);
  else
    gemm3<1, false, false><<<256, 512, 0, stream>>>(in_w, xpad, in_b, hpA);

  for (int l = 0; l < 20; ++l) {
    const f16* cur = (l % 2 == 0) ? hpA : hpB;
    f16* nxt = (l % 2 == 0) ? hpB : hpA;
    if (pre)
      gemm3<32, true, true><<<256, 512, 0, stream>>>(
          WfH + (size_t)l * 1048576, cur, convs_b + 32 * l, nxt);
    else
      gemm3<32, true, false><<<256, 512, 0, stream>>>(
          convs_w + (size_t)l * 1048576, cur, convs_b + 32 * l, nxt);
  }

  // after l=19 (odd): output in hpA
  out_conv3<<<64, 256, 0, stream>>>(hpA, out_w, out_b, out);
}

// Round 3
// 948.250 us; speedup vs baseline: 1.0577x; 1.0320x over previous
//
#include <hip/hip_runtime.h>

// GoL CNN v5: scheduling rework of v4.
//  - 4-deep rowbuf ring, block barrier every 2 K-steps (16/layer, was 32):
//    waves drift a full K-step -> MFMA of one wave overlaps LDS of another.
//  - all LDS gather addresses hoisted out of the K-loop (24 per-lane
//    pointers, buf x row); steady-state gathers are ds_read2_b32 with
//    immediate offsets, zero per-iteration address VALU.
//  - staging loads issued ~2 bodies before their ds_write (latency hidden),
//    A-frag prefetch depth 1 (registers, fly across barriers).
// Math identical to v4 (consecutive-ky, 12 gathers / 16 MFMA per wave per c).

typedef _Float16 f16;
typedef _Float16 f16x8 __attribute__((ext_vector_type(8)));
typedef float f32x4 __attribute__((ext_vector_type(4)));
typedef float f32x16 __attribute__((ext_vector_type(16)));

// iterated wrap-pad index map, j in [0,94): middle j-31; borders alternate.
__device__ __forceinline__ int mwrap(int j) {
  int t = j - 31;
  if ((unsigned)t <= 31u) return t;          // middle
  if (t < 0) return (j & 1) ? 0 : 31;        // left border
  return (j & 1) ? 0 : 31;                   // right border
}

// hpad layout: [16b][32ch][32y][96x] f16 (x' in [0,94) valid)
// Wf frag-major: per layer, chunk=(c*32+ky)*2+kxh, then [lane(64)][8 f16]
//   lane: co=lane&31, s=lane>>5; elements w[co][c][ky][kxh*16+s*8+j]

// One K-step: 12 gathers (6 rows x 2 kxh) + 16 MFMA. PB = hoisted pointer
// array for the buffer (literal!), AUSE = A-frag register set.
#define GOLBODY(PB, AUSE)                                                   \
  {                                                                         \
    f16x8 F[6][2];                                                          \
    _Pragma("unroll")                                                       \
    for (int j_ = 0; j_ < 6; ++j_) {                                        \
      int4 t0_, t1_;                                                        \
      t0_.x = PB[j_][0]; t0_.y = PB[j_][1];                                 \
      t0_.z = PB[j_][2]; t0_.w = PB[j_][3];                                 \
      t1_.x = PB[j_][8]; t1_.y = PB[j_][9];                                 \
      t1_.z = PB[j_][10]; t1_.w = PB[j_][11];                               \
      F[j_][0] = __builtin_bit_cast(f16x8, t0_);                            \
      F[j_][1] = __builtin_bit_cast(f16x8, t1_);                            \
    }                                                                       \
    _Pragma("unroll")                                                       \
    for (int kyi_ = 0; kyi_ < 4; ++kyi_) {                                  \
      _Pragma("unroll")                                                     \
      for (int kxh_ = 0; kxh_ < 2; ++kxh_) {                                \
        const f16x8 a_ = AUSE[kyi_ * 2 + kxh_];                             \
        acc0 = __builtin_amdgcn_mfma_f32_32x32x16_f16(a_, F[kyi_][kxh_],    \
                                                      acc0, 0, 0, 0);       \
        acc1 = __builtin_amdgcn_mfma_f32_32x32x16_f16(a_, F[kyi_ + 2][kxh_],\
                                                      acc1, 0, 0, 0);       \
      }                                                                     \
    }                                                                       \
  }

// Producer barrier: drain LDS ops only; VMEM (weight/stage loads) stays
// in flight. sched_barrier pins the region (rule #18).
#define GOLBAR()                                       \
  asm volatile("s_waitcnt lgkmcnt(0)" ::: "memory");   \
  __builtin_amdgcn_sched_barrier(0);                   \
  __builtin_amdgcn_s_barrier();

template <int CIN, bool RELU, bool PRE>
__global__ __launch_bounds__(512, 2) void gemm3(
    const void* __restrict__ Wv,       // PRE: f16 frag-major; else fp32 raw
    const f16* __restrict__ hp_in,     // [16][CIN][32][96]
    const float* __restrict__ bias,    // [32]
    f16* __restrict__ hp_out) {        // [16][32][32][96]
  __shared__ __align__(16) f16 rowbuf[4][32][96];  // 24 KB ring
  __shared__ float Red[8][2][1024];                // 64 KB

  const int tid = threadIdx.x;
  const int lane = tid & 63;
  const int w = tid >> 6;        // wave 0..7: owns ky in {4w..4w+3}
  const int ox = lane & 31;      // B n-index / A m-index (co)
  const int s = lane >> 5;       // k-half within mfma

  const int pair0 = blockIdx.x * 2;
  const int b = pair0 >> 5;
  const int oy0 = pair0 & 31;    // pair0 even -> oy0, oy0+1 same batch

  // row staging decode: 384 units of f16x8 cover 32 rows x 96 (waves 0-5)
  const int rrow = tid / 12, rseg = tid - rrow * 12;  // valid if tid<384

  // input rows needed by this wave (loop-invariant across c):
  // acc0 (row oy0):   y = mwrap(2*oy0 + 4w + kyi)      -> j = kyi
  // acc1 (row oy0+1): y = mwrap(2*oy0 + 2 + 4w + kyi)  -> j = kyi+2
  int ybase[6];
#pragma unroll
  for (int j = 0; j < 6; ++j) ybase[j] = mwrap(2 * oy0 + 4 * w + j);

  // hoisted per-lane LDS gather pointers: kxh handled via +8-dword imm off
  const int bi = ox + 4 * s;
  const int *P0[6], *P1[6], *P2[6], *P3[6];
#pragma unroll
  for (int j = 0; j < 6; ++j) {
    P0[j] = (const int*)(&rowbuf[0][ybase[j]][0]) + bi;
    P1[j] = (const int*)(&rowbuf[1][ybase[j]][0]) + bi;
    P2[j] = (const int*)(&rowbuf[2][ybase[j]][0]) + bi;
    P3[j] = (const int*)(&rowbuf[3][ybase[j]][0]) + bi;
  }

  f32x16 acc0 = {}, acc1 = {};   // per pair
  f16x8 A0[8], A1[8];
  f16x8 stgA = {}, stgB = {};

  auto loadA = [&](int c, f16x8* dst) {
#pragma unroll
    for (int kyi = 0; kyi < 4; ++kyi) {
#pragma unroll
      for (int kxh = 0; kxh < 2; ++kxh) {
        const int ky = 4 * w + kyi;
        const int chunk = (c * 32 + ky) * 2 + kxh;
        if constexpr (PRE) {
          const f16* Wl = (const f16*)Wv;
          dst[kyi * 2 + kxh] = *(const f16x8*)(Wl + (size_t)chunk * 512 + lane * 8);
        } else {
          const float* Wl = (const float*)Wv;
          const float* sp = Wl + (((size_t)(ox * CIN + c) * 32 + ky) * 32 + kxh * 16 + s * 8);
          f32x4 u0 = *(const f32x4*)sp;
          f32x4 u1 = *(const f32x4*)(sp + 4);
          f16x8 v;
          v[0] = (f16)u0[0]; v[1] = (f16)u0[1]; v[2] = (f16)u0[2]; v[3] = (f16)u0[3];
          v[4] = (f16)u1[0]; v[5] = (f16)u1[1]; v[6] = (f16)u1[2]; v[7] = (f16)u1[3];
          dst[kyi * 2 + kxh] = v;
        }
      }
    }
  };
  auto loadRowTo = [&](int c, f16x8& dst) {
    if (tid < 384)
      dst = *(const f16x8*)(hp_in + ((size_t)(b * CIN + c) * 32 + rrow) * 96 + rseg * 8);
  };
  auto writeRow = [&](int nb, const f16x8& src) {
    if (tid < 384) *(f16x8*)(&rowbuf[nb][rrow][rseg * 8]) = src;
  };

  if constexpr (CIN == 1) {
    loadRowTo(0, stgA);
    writeRow(0, stgA);
    loadA(0, A0);
    __syncthreads();
    GOLBODY(P0, A0);
  } else {
    static_assert(CIN % 4 == 0, "CIN must be 1 or multiple of 4");
    loadRowTo(0, stgA);
    loadRowTo(1, stgB);
    writeRow(0, stgA);
    writeRow(1, stgB);
    loadA(0, A0);
    __syncthreads();

#pragma unroll 1
    for (int gg = 0; gg < CIN / 4; ++gg) {
      const int c0 = 4 * gg;
      // ---- half 1: compute c0 (buf0), c0+1 (buf1); stage c0+2,c0+3 -> bufs 2,3
      loadRowTo(c0 + 2, stgA);
      loadRowTo(c0 + 3, stgB);
      loadA(c0 + 1, A1);
      GOLBODY(P0, A0);
      loadA(c0 + 2, A0);
      GOLBODY(P1, A1);
      writeRow(2, stgA);
      writeRow(3, stgB);
      GOLBAR();
      // ---- half 2: compute c0+2 (buf2), c0+3 (buf3); stage c0+4,c0+5 -> bufs 0,1
      const bool more = (c0 + 4 < CIN);
      if (more) {
        loadRowTo(c0 + 4, stgA);
        loadRowTo(c0 + 5, stgB);
      }
      loadA(c0 + 3, A1);
      GOLBODY(P2, A0);
      if (more) loadA(c0 + 4, A0);
      GOLBODY(P3, A1);
      if (more) {
        writeRow(0, stgA);
        writeRow(1, stgB);
        GOLBAR();
      }
    }
  }

  // one-shot 8-way K reduction: every wave dumps, all 512 threads re-reduce
#pragma unroll
  for (int r = 0; r < 16; ++r) {
    Red[w][0][r * 64 + lane] = acc0[r];
    Red[w][1][r * 64 + lane] = acc1[r];
  }
  __syncthreads();

#pragma unroll
  for (int k4 = 0; k4 < 4; ++k4) {
    const int o = tid + 512 * k4;          // 2048 outputs: [p][co][ox]
    const int p = o >> 10, co = (o >> 5) & 31, oxx = o & 31;
    const int idx = ((co & 3) + 4 * (co >> 3)) * 64 + ((co >> 2) & 1) * 32 + oxx;
    float v = bias[co];
#pragma unroll
    for (int w8 = 0; w8 < 8; ++w8) v += Red[w8][p][idx];
    if (RELU) v = fmaxf(v, 0.f);
    const f16 hv = (f16)v;
    f16* base = hp_out + ((size_t)(b * 32 + co) * 32 + (oy0 + p)) * 96;
    base[oxx + 31] = hv;
    if (oxx == 0) {
#pragma unroll
      for (int j = 1; j <= 29; j += 2) base[j] = hv;
#pragma unroll
      for (int j = 63; j <= 93; j += 2) base[j] = hv;
    }
    if (oxx == 31) {
#pragma unroll
      for (int j = 0; j <= 30; j += 2) base[j] = hv;
#pragma unroll
      for (int j = 64; j <= 92; j += 2) base[j] = hv;
    }
  }
}

// x (fp32 [16][1][32][32]) -> xpad f16 [16][1][32][96]
__global__ void pad_x_kernel(const float* __restrict__ x, f16* __restrict__ xp) {
  const int i = blockIdx.x * 256 + threadIdx.x;  // 16*32*94 = 48128
  if (i >= 48128) return;
  const int bq = i / 3008, r = i - bq * 3008;
  const int y = r / 94, j = r - y * 94;
  xp[bq * 3072 + y * 96 + j] = (f16)x[(bq * 32 + y) * 32 + mwrap(j)];
}

// build frag-major f16 weights: in_w (64 chunks) + 20 hidden layers (2048 each)
__global__ void convert_w3(const float* __restrict__ in_w,
                           const float* __restrict__ convs_w,
                           f16* __restrict__ WfIn, f16* __restrict__ WfH) {
  const int total = 4096 + 20 * 131072;  // units of (chunk,lane)
  for (int g = blockIdx.x * blockDim.x + threadIdx.x; g < total;
       g += gridDim.x * blockDim.x) {
    const float* src;
    f16* dst;
    int chunk, lanE, c, ky, kxh;
    if (g < 4096) {
      chunk = g >> 6; lanE = g & 63;
      kxh = chunk & 1; ky = chunk >> 1; c = 0;
      const int co = lanE & 31, ss = lanE >> 5;
      src = in_w + ((size_t)(co * 1 + 0) * 32 + ky) * 32 + kxh * 16 + ss * 8;
      dst = WfIn + (size_t)chunk * 512 + lanE * 8;
    } else {
      const int h = g - 4096;
      const int layer = h >> 17, r = h & 131071;
      chunk = r >> 6; lanE = r & 63;
      kxh = chunk & 1;
      const int t = chunk >> 1;
      ky = t & 31; c = t >> 5;
      const int co = lanE & 31, ss = lanE >> 5;
      src = convs_w + (size_t)layer * 1048576 +
            ((size_t)(co * 32 + c) * 32 + ky) * 32 + kxh * 16 + ss * 8;
      dst = WfH + (size_t)layer * 1048576 + (size_t)chunk * 512 + lanE * 8;
    }
    f32x4 u0 = *(const f32x4*)src;
    f32x4 u1 = *(const f32x4*)(src + 4);
    f16x8 v;
    v[0] = (f16)u0[0]; v[1] = (f16)u0[1]; v[2] = (f16)u0[2]; v[3] = (f16)u0[3];
    v[4] = (f16)u1[0]; v[5] = (f16)u1[1]; v[6] = (f16)u1[2]; v[7] = (f16)u1[3];
    *(f16x8*)dst = v;
  }
}

// 1x1 out conv from hpad final: out[b][0][oy][ox] fp32
__global__ void out_conv3(const f16* __restrict__ hp,
                          const float* __restrict__ ow,
                          const float* __restrict__ ob,
                          float* __restrict__ out) {
  const int o = blockIdx.x * 256 + threadIdx.x;  // 16384
  const int b = o >> 10, oy = (o >> 5) & 31, oxx = o & 31;
  float s = ob[0];
#pragma unroll
  for (int c = 0; c < 32; ++c)
    s += ow[c] * (float)hp[((size_t)(b * 32 + c) * 32 + oy) * 96 + oxx + 31];
  out[o] = s;
}

extern "C" void kernel_launch(void* const* d_in, const int* in_sizes, int n_in,
                              void* d_out, int out_size, void* d_ws,
                              size_t ws_size, hipStream_t stream) {
  const float* x = (const float*)d_in[0];
  const float* in_w = (const float*)d_in[1];
  const float* in_b = (const float*)d_in[2];
  const float* convs_w = (const float*)d_in[3];
  const float* convs_b = (const float*)d_in[4];
  const float* out_w = (const float*)d_in[5];
  const float* out_b = (const float*)d_in[6];
  float* out = (float*)d_out;

  char* ws = (char*)d_ws;
  f16* xpad = (f16*)ws;                               //    98,304 B
  f16* hpA = (f16*)(ws + 98304);                      // 3,145,728 B
  f16* hpB = (f16*)(ws + 98304 + 3145728);            // 3,145,728 B
  f16* WfIn = (f16*)(ws + 6389760);                   //    65,536 B
  f16* WfH = (f16*)(ws + 6455296);                    // 41,943,040 B
  const bool pre = (ws_size >= 48398336ull);

  pad_x_kernel<<<188, 256, 0, stream>>>(x, xpad);
  if (pre) convert_w3<<<2048, 256, 0, stream>>>(in_w, convs_w, WfIn, WfH);

  if (pre)
    gemm3<1, false, true><<<256, 512, 0, stream>>>(WfIn, xpad, in_b, hpA);
  else
    gemm3<1, false, false><<<256, 512, 0, stream>>>(in_w, xpad, in_b, hpA);

  for (int l = 0; l < 20; ++l) {
    const f16* cur = (l % 2 == 0) ? hpA : hpB;
    f16* nxt = (l % 2 == 0) ? hpB : hpA;
    if (pre)
      gemm3<32, true, true><<<256, 512, 0, stream>>>(
          WfH + (size_t)l * 1048576, cur, convs_b + 32 * l, nxt);
    else
      gemm3<32, true, false><<<256, 512, 0, stream>>>(
          convs_w + (size_t)l * 1048576, cur, convs_b + 32 * l, nxt);
  }

  // after l=19 (odd): output in hpA
  out_conv3<<<64, 256, 0, stream>>>(hpA, out_w, out_b, out);
}